// Round 13
// baseline (6113.152 us; speedup 1.0000x reference)
//
#include <hip/hip_runtime.h>
#include <hip/hip_bf16.h>

// ESN persistent pipeline v7: no-address-reuse slots => per-XCD L2 sharing.
// BIG path (ws_size >= ~251MB): 512 slots (one per step, never reused) ->
//   consumers read h with sc0-only loads (L1 bypass, L2 INSTALL+HIT; cold
//   misses only, since addresses are fresh within a launch). Cross-replay
//   staleness killed by one launch-time buffer_inv sc1 per block, which is
//   safe because ALL stores (k_pack, h, out) are sc0sc1 write-through ->
//   nothing is ever dirty for inv to drop (R9's corruption = k_pack's plain
//   dirty lines + graph fence elision). No WAR polls, no leaders.
// SMALL fallback: exact R12 behavior (8 slots, sc0sc1 loads, no inv).
// Weights AGPR-resident via inline-asm MFMA "a" operand (R12, verified).

typedef unsigned short u16;
typedef __attribute__((ext_vector_type(8))) __bf16 bf16x8;
typedef __attribute__((ext_vector_type(4))) float f32x4;

#define MFMA_AG(acc, a, w) \
  asm volatile("v_mfma_f32_16x16x32_bf16 %0, %1, %2, %0" : "+v"(acc) : "v"(a), "a"(w))

#define KC0 72
#define KC1 128
#define KCP 192
#define E0P (128*KC0*512)
#define E1P (128*KC1*512)
#define EPP (8*KCP*512)
#define CH 1024                // u16 per chunk
#define S0 (68*CH)             // H0 slot: 64 h-chunks + 4 pad chunks
#define S12 (64*CH)
#define NSLOT 8                // small-path slots

static __device__ __forceinline__ float b2f(u16 u){ return __uint_as_float(((unsigned)u)<<16); }
static __device__ __forceinline__ u16 f2b(float f){ unsigned x=__float_as_uint(f); return (u16)((x + 0x7FFFu + ((x>>16)&1u))>>16); }
static __device__ __forceinline__ int frag_addr(int b, int j){
  int c=j>>5, ko=j&31, half=b>>4, lane=(b&15)|((ko>>3)<<4), e=ko&7;
  return ((c*2+half)*64+lane)*8+e;
}
static __device__ __forceinline__ bf16x8 asbf(f32x4 v){ union U{f32x4 f; bf16x8 b;} u; u.f=v; return u.b; }

// ---- memory primitives ----
template<int BIG>
static __device__ __forceinline__ f32x4 ld_act(const u16* p){
  f32x4 r;
  if constexpr (BIG) asm volatile("global_load_dwordx4 %0, %1, off sc0" : "=v"(r) : "v"(p));
  else               asm volatile("global_load_dwordx4 %0, %1, off sc0 sc1" : "=v"(r) : "v"(p));
  return r;
}
static __device__ __forceinline__ f32x4 ld16_pl(const float* p){
  f32x4 r;
  asm volatile("global_load_dwordx4 %0, %1, off" : "=v"(r) : "v"(p));
  return r;
}
static __device__ __forceinline__ void st_b128_sc(u16* p, f32x4 v){
  asm volatile("global_store_dwordx4 %0, %1, off sc0 sc1" :: "v"(p), "v"(v) : "memory");
}
static __device__ __forceinline__ void st_f32_sc(float* p, float v){
  asm volatile("global_store_dword %0, %1, off sc0 sc1" :: "v"(p), "v"(v) : "memory");
}
static __device__ __forceinline__ void st_b32_sc(unsigned* p, unsigned v){
  asm volatile("global_store_dword %0, %1, off sc0 sc1" :: "v"(p), "v"(v) : "memory");
}
static __device__ __forceinline__ void drain(){
  asm volatile("s_waitcnt vmcnt(0)" ::: "memory");
}
static __device__ __forceinline__ void l2_cleanse(){
  asm volatile("buffer_inv sc1\n\ts_waitcnt vmcnt(0)" ::: "memory");
}
#define WAITV(n) do{ asm volatile("s_waitcnt vmcnt(" #n ")" ::: "memory"); __builtin_amdgcn_sched_barrier(0); }while(0)

// wave-parallel seqno poll: wave 0, lane i watches producer i.
static __device__ __forceinline__ void poll4(int lane,
    const unsigned* a, unsigned ta,
    const unsigned* b, unsigned tb,
    const unsigned* c, unsigned tc, int nc,
    const unsigned* d, unsigned td)
{
  for(;;){
    unsigned va=0, vb=0, vc=0, vd=0;
    asm volatile("global_load_dword %0, %1, off sc0 sc1" : "=v"(va) : "v"(a+lane));
    if (b) asm volatile("global_load_dword %0, %1, off sc0 sc1" : "=v"(vb) : "v"(b+lane));
    if (c) asm volatile("global_load_dword %0, %1, off sc0 sc1" : "=v"(vc) : "v"(c+(lane<nc?lane:0)));
    if (d) asm volatile("global_load_dword %0, %1, off sc0 sc1" : "=v"(vd) : "v"(d+(lane<8?lane:0)));
    asm volatile("s_waitcnt vmcnt(0)" ::: "memory");
    __builtin_amdgcn_sched_barrier(0);
    bool ok = (va>=ta);
    if (b) ok &= (vb>=tb);
    if (c) ok &= (lane>=nc) || (vc>=tc);
    if (d) ok &= (lane>=8) || (vd>=td);
    if (__all(ok)) return;
    __builtin_amdgcn_s_sleep(1);
  }
}

// ---------------- weight pack: now sc0sc1 write-through (nothing dirty) ----------------
__global__ __launch_bounds__(256) void k_pack(const float* __restrict__ wih0, const float* __restrict__ whh0,
    const float* __restrict__ wih1, const float* __restrict__ whh1,
    const float* __restrict__ wih2, const float* __restrict__ whh2,
    const float* __restrict__ wout,
    u16* __restrict__ p0, u16* __restrict__ p1, u16* __restrict__ p2, u16* __restrict__ po)
{
  const long SRC0 = 2048L*2176, SRC1 = 2048L*4096, SRCP = 128L*6144;
  const long total8 = (SRC0 + 2*SRC1 + SRCP) >> 3;
  for (long id = (long)blockIdx.x*blockDim.x + threadIdx.x; id < total8; id += (long)gridDim.x*blockDim.x){
    long r = id<<3; int KC, j, k; u16* dst;
    const float* sa; const float* sb; int split;
    if (r < SRC0){ KC=KC0; j=(int)(r/2176); k=(int)(r%2176); sa=wih0+(size_t)j*128; sb=whh0+(size_t)j*2048; split=128; dst=p0; }
    else if ((r -= SRC0) < SRC1){ KC=KC1; j=(int)(r/4096); k=(int)(r%4096); sa=wih1+(size_t)j*2048; sb=whh1+(size_t)j*2048; split=2048; dst=p1; }
    else if ((r -= SRC1) < SRC1){ KC=KC1; j=(int)(r/4096); k=(int)(r%4096); sa=wih2+(size_t)j*2048; sb=whh2+(size_t)j*2048; split=2048; dst=p2; }
    else { r -= SRC1; KC=KCP; j=(int)(r/6144); k=(int)(r%6144); sa=wout+(size_t)j*6144; sb=sa; split=6144; dst=po; }
    const float* src = (k<split) ? (sa + k) : (sb + (k - split));
    u16 tmp[8];
    #pragma unroll
    for (int e=0;e<8;e++) tmp[e] = f2b(src[e]);
    int jt=j>>4, jl=j&15, c=k>>5, ko=k&31, lane=((ko>>3)<<4)|jl;
    u16* dp = dst + (((size_t)jt*KC + c)*64 + lane)*8;
    st_b128_sc(dp, *(f32x4*)tmp);
  }
}

// ---- L12 rolling staging: 8 slots, 16 chunks ----
#define L12_ISS(s0, c0) \
  _Pragma("unroll") \
  for (int i=0;i<4;++i){ \
    sa[(s0)+i]=ld_act<BIG>(apb + (size_t)((c0)+i)*CH); \
    sb[(s0)+i]=ld_act<BIG>(apb + (size_t)((c0)+i)*CH + 512); \
  }
#define L12_MM(s0, c0) \
  _Pragma("unroll") \
  for (int i=0;i<4;++i){ \
    bf16x8 a0=asbf(sa[(s0)+i]), a1=asbf(sb[(s0)+i]); \
    MFMA_AG(acc00,a0,wreg[0][(c0)+i]); MFMA_AG(acc01,a1,wreg[0][(c0)+i]); \
    MFMA_AG(acc10,a0,wreg[1][(c0)+i]); MFMA_AG(acc11,a1,wreg[1][(c0)+i]); \
  }
#define PIN_ACC4() asm volatile("s_nop 1" : "+v"(acc00), "+v"(acc01), "+v"(acc10), "+v"(acc11))
#define FENCE_ACC4() asm volatile("s_nop 7\n\ts_nop 7" : "+v"(acc00), "+v"(acc01), "+v"(acc10), "+v"(acc11))

// ---------------- layer 1/2 persistent loop ----------------
template<int BIG>
static __device__ __forceinline__ void run_l12(
    const u16* __restrict__ pW, const float* __restrict__ bias,
    const u16* __restrict__ A0slots, size_t a0stride, u16* OWN, const u16* OWNZ,
    unsigned* SEQup, unsigned* SEQown, unsigned* Sc, int nc, unsigned* Sd,
    int jt0, float (*red)[2][2][256], u16* ldsout)
{
  const int tid=threadIdx.x, w=tid>>6, ln=tid&63;
  bf16x8 wreg[2][16];            // -> AGPRs
  #pragma unroll
  for (int u=0;u<2;u++)
    #pragma unroll
    for (int ci=0;ci<16;ci++)
      wreg[u][ci] = *(const bf16x8*)(pW + (((size_t)(jt0+u)*KC1 + (w*16+ci))*64 + ln)*8);

  const int h_=tid>>8, pos=tid&255, l_=pos>>2, i_=pos&3, col_=l_&15, row_=((l_>>4)<<2)+i_, b_=(h_<<4)+row_;
  const float bv0=bias[(jt0<<4)+col_], bv1=bias[((jt0+1)<<4)+col_];
  const int ko0=col_, ko1=16+col_;
  const int faw0=((h_*64)+((b_&15)|((ko0>>3)<<4)))*8+(ko0&7);
  const int faw1=((h_*64)+((b_&15)|((ko1>>3)<<4)))*8+(ko1&7);
  const int myc=jt0>>1, gidx=jt0>>1;

  if (tid<128) *(f32x4*)(ldsout+tid*8) = (f32x4){0,0,0,0};
  __syncthreads();

  for (int t=0;t<512;t++){
    if (tid<64){
      if constexpr (BIG)
        poll4(tid, SEQup,(unsigned)(t+1), SEQown,(unsigned)t, nullptr,0u,0, nullptr,0u);
      else
        poll4(tid, SEQup,(unsigned)(t+1), SEQown,(unsigned)t,
              (t>=NSLOT)?Sc:nullptr,(unsigned)(t-7),nc,
              (t>=NSLOT)?Sd:nullptr,(unsigned)(t-7));
    }
    __syncthreads();
    const u16* xa = A0slots + (size_t)(BIG ? t : (t&7))*a0stride;
    const u16* xb = BIG ? (t==0 ? OWNZ : OWN + (size_t)(t-1)*S12)
                        : OWN + (size_t)((t+7)&7)*S12;
    u16* hc = OWN + (size_t)(BIG ? t : (t&7))*S12;
    const u16* a0base = (w<4) ? xa + (size_t)(w*16)*CH : xb + (size_t)((w-4)*16)*CH;
    const u16* apb = a0base + (size_t)ln*8;
    f32x4 sa[8], sb[8];
    f32x4 acc00={0,0,0,0},acc01={0,0,0,0},acc10={0,0,0,0},acc11={0,0,0,0};
    PIN_ACC4();
    L12_ISS(0,0); L12_ISS(4,4);
    WAITV(8); L12_MM(0,0); L12_ISS(0,8);
    WAITV(8); L12_MM(4,4); L12_ISS(4,12);
    WAITV(8); L12_MM(0,8);
    WAITV(0); L12_MM(4,12);
    FENCE_ACC4();
    #pragma unroll
    for (int i=0;i<4;i++){
      red[w][0][0][(ln<<2)+i]=acc00[i]; red[w][0][1][(ln<<2)+i]=acc01[i];
      red[w][1][0][(ln<<2)+i]=acc10[i]; red[w][1][1][(ln<<2)+i]=acc11[i];
    }
    __syncthreads();
    {
      float v0=0.f, v1=0.f;
      #pragma unroll
      for (int ww=0;ww<8;ww++){ v0 += red[ww][0][h_][pos]; v1 += red[ww][1][h_][pos]; }
      float hp0 = b2f(ldsout[faw0]);
      float hp1 = b2f(ldsout[faw1]);
      ldsout[faw0] = f2b(0.05f*hp0 + 0.95f*tanhf(v0 + bv0));
      ldsout[faw1] = f2b(0.05f*hp1 + 0.95f*tanhf(v1 + bv1));
    }
    __syncthreads();
    if (tid<128){
      f32x4 vv = *(const f32x4*)(ldsout + tid*8);
      st_b128_sc(hc + (size_t)myc*CH + tid*8, vv);
    }
    drain();
    __syncthreads();
    if (tid==0) st_b32_sc(SEQown+gidx, (unsigned)(t+1));
  }
}

// ---- L0 staged-load macros ----
#define X_ISSUE(ci) do{ \
    const float* q0 = xf + rr*128 + (ci)*32 + kg*8; \
    xs0[ci]=ld16_pl(q0); xs1[ci]=ld16_pl(q0+4); \
    xs2[ci]=ld16_pl(q0+2048); xs3[ci]=ld16_pl(q0+2052); \
  }while(0)
#define X_MFMA(ci) do{ \
    bf16x8 a0,a1; \
    _Pragma("unroll") \
    for (int e=0;e<4;e++){ a0[e]=(__bf16)xs0[ci][e]; a0[e+4]=(__bf16)xs1[ci][e]; \
                           a1[e]=(__bf16)xs2[ci][e]; a1[e+4]=(__bf16)xs3[ci][e]; } \
    asm volatile("s_nop 1" : "+v"(a0), "+v"(a1)); \
    MFMA_AG(acc00,a0,wreg[0][ci]); MFMA_AG(acc01,a1,wreg[0][ci]); \
    MFMA_AG(acc10,a0,wreg[1][ci]); MFMA_AG(acc11,a1,wreg[1][ci]); \
  }while(0)
#define LH_ISSUE(ci) do{ sa[ci]=ld_act<BIG>(hbp + (size_t)(ci)*CH); sb[ci]=ld_act<BIG>(hbp + (size_t)(ci)*CH + 512); }while(0)
#define LH_MFMA(ci) do{ \
    bf16x8 a0=asbf(sa[ci]), a1=asbf(sb[ci]); \
    MFMA_AG(acc00,a0,wreg[0][ci]); MFMA_AG(acc01,a1,wreg[0][ci]); \
    MFMA_AG(acc10,a0,wreg[1][ci]); MFMA_AG(acc11,a1,wreg[1][ci]); \
  }while(0)

// ---------------- layer 0 persistent loop ----------------
template<int BIG>
static __device__ __forceinline__ void run_l0(
    const u16* __restrict__ pW, const float* __restrict__ bias, const float* __restrict__ input,
    u16* H0, const u16* HZ0, unsigned* SEQ0, unsigned* SEQ1, unsigned* SEQ3,
    int jt0, float (*red)[2][2][256], u16* ldsout)
{
  const int tid=threadIdx.x, w=tid>>6, ln=tid&63, rr=ln&15, kg=ln>>4;
  bf16x8 wreg[2][9];             // -> AGPRs
  #pragma unroll
  for (int u=0;u<2;u++)
    #pragma unroll
    for (int ci=0;ci<9;ci++)
      wreg[u][ci] = *(const bf16x8*)(pW + (((size_t)(jt0+u)*KC0 + (w*9+ci))*64 + ln)*8);

  const int h_=tid>>8, pos=tid&255, l_=pos>>2, i_=pos&3, col_=l_&15, row_=((l_>>4)<<2)+i_, b_=(h_<<4)+row_;
  const float bv0=bias[(jt0<<4)+col_], bv1=bias[((jt0+1)<<4)+col_];
  const int ko0=col_, ko1=16+col_;
  const int faw0=((h_*64)+((b_&15)|((ko0>>3)<<4)))*8+(ko0&7);
  const int faw1=((h_*64)+((b_&15)|((ko1>>3)<<4)))*8+(ko1&7);
  const int myc=jt0>>1, gidx=jt0>>1;

  if (tid<128) *(f32x4*)(ldsout+tid*8) = (f32x4){0,0,0,0};
  __syncthreads();

  for (int t=0;t<512;t++){
    if (tid<64){
      if constexpr (BIG)
        poll4(tid, SEQ0,(unsigned)t, nullptr,0u, nullptr,0u,0, nullptr,0u);
      else
        poll4(tid, SEQ0,(unsigned)t, (t>=NSLOT)?SEQ1:nullptr,(unsigned)(t-7),
              (t>=NSLOT)?SEQ3:nullptr,(unsigned)(t-7),8, nullptr,0u);
    }
    __syncthreads();
    const float* xf = input + (size_t)t*4096;
    const u16* h0prv = BIG ? (t==0 ? HZ0 : H0 + (size_t)(t-1)*S0)
                           : H0 + (size_t)((t+7)&7)*S0;
    u16* hc = H0 + (size_t)(BIG ? t : (t&7))*S0;
    f32x4 acc00={0,0,0,0},acc01={0,0,0,0},acc10={0,0,0,0},acc11={0,0,0,0};
    PIN_ACC4();
    if (w==0){
      f32x4 xs0[4],xs1[4],xs2[4],xs3[4], sa[9], sb[9];
      const u16* hbp = h0prv - (size_t)4*CH + (size_t)ln*8;  // deref only at ci>=4
      X_ISSUE(0); X_ISSUE(1);
      X_ISSUE(2); X_ISSUE(3); WAITV(8); X_MFMA(0); X_MFMA(1);
      LH_ISSUE(4); LH_ISSUE(5); LH_ISSUE(6); LH_ISSUE(7); LH_ISSUE(8);
      WAITV(10); X_MFMA(2); X_MFMA(3);
      WAITV(0);
      LH_MFMA(4); LH_MFMA(5); LH_MFMA(6); LH_MFMA(7); LH_MFMA(8);
    } else {
      f32x4 sa[9], sb[9];
      const u16* hbp = h0prv + (size_t)(w*9-4)*CH + (size_t)ln*8;
      LH_ISSUE(0); LH_ISSUE(1); LH_ISSUE(2); LH_ISSUE(3);
      LH_ISSUE(4); LH_ISSUE(5); LH_ISSUE(6); LH_ISSUE(7);
      WAITV(8);  LH_MFMA(0); LH_MFMA(1); LH_MFMA(2); LH_MFMA(3);
      LH_ISSUE(8);
      WAITV(2);  LH_MFMA(4); LH_MFMA(5); LH_MFMA(6); LH_MFMA(7);
      WAITV(0);  LH_MFMA(8);
    }
    FENCE_ACC4();
    #pragma unroll
    for (int i=0;i<4;i++){
      red[w][0][0][(ln<<2)+i]=acc00[i]; red[w][0][1][(ln<<2)+i]=acc01[i];
      red[w][1][0][(ln<<2)+i]=acc10[i]; red[w][1][1][(ln<<2)+i]=acc11[i];
    }
    __syncthreads();
    {
      float v0=0.f, v1=0.f;
      #pragma unroll
      for (int ww=0;ww<8;ww++){ v0 += red[ww][0][h_][pos]; v1 += red[ww][1][h_][pos]; }
      float hp0 = b2f(ldsout[faw0]);
      float hp1 = b2f(ldsout[faw1]);
      ldsout[faw0] = f2b(0.05f*hp0 + 0.95f*tanhf(v0 + bv0));
      ldsout[faw1] = f2b(0.05f*hp1 + 0.95f*tanhf(v1 + bv1));
    }
    __syncthreads();
    if (tid<128){
      f32x4 vv = *(const f32x4*)(ldsout + tid*8);
      st_b128_sc(hc + (size_t)myc*CH + tid*8, vv);
    }
    drain();
    __syncthreads();
    if (tid==0) st_b32_sc(SEQ0+gidx, (unsigned)(t+1));
  }
}

// ---- proj rolling staging: 12 slots, 24 chunks ----
#define P_AP(kc_) ((kc_)<64 ? h0c+(size_t)(kc_)*CH : ((kc_)<128 ? h1c+(size_t)((kc_)-64)*CH : h2c+(size_t)((kc_)-128)*CH))
#define P_ISS(s0, c0) \
  _Pragma("unroll") \
  for (int i=0;i<6;++i){ \
    const u16* ap = P_AP(w*24+(c0)+i) + (size_t)ln*8; \
    sa[(s0)+i]=ld_act<BIG>(ap); sb[(s0)+i]=ld_act<BIG>(ap+512); \
  }
#define P_MM(s0, c0) \
  _Pragma("unroll") \
  for (int i=0;i<6;++i){ \
    bf16x8 a0=asbf(sa[(s0)+i]), a1=asbf(sb[(s0)+i]); \
    MFMA_AG(acc0,a0,wreg[(c0)+i]); MFMA_AG(acc1,a1,wreg[(c0)+i]); \
  }

// ---------------- projection persistent loop + final-h epilogue ----------------
template<int BIG>
static __device__ __forceinline__ void run_proj(
    const u16* __restrict__ pW, const float* __restrict__ bo,
    const u16* __restrict__ H0, const u16* __restrict__ H1, const u16* __restrict__ H2,
    float* __restrict__ out, const int* __restrict__ washp,
    unsigned* SEQ0, unsigned* SEQ1, unsigned* SEQ2, unsigned* SEQ3,
    int jt, float (*red)[2][2][256])
{
  const int tid=threadIdx.x, w=tid>>6, ln=tid&63;
  bf16x8 wreg[24];               // -> AGPRs
  #pragma unroll
  for (int ci=0;ci<24;ci++)
    wreg[ci] = *(const bf16x8*)(pW + (((size_t)jt*KCP + (w*24+ci))*64 + ln)*8);
  const int wash = *washp;
  const int h_=tid>>8, pos=tid&255, l_=pos>>2, i_=pos&3, col_=l_&15, row_=((l_>>4)<<2)+i_, b_=(h_<<4)+row_;
  const float bvp = bo[(jt<<4)+col_];

  for (int t=0;t<512;t++){
    if (tid<64){
      poll4(tid, SEQ0,(unsigned)(t+1), SEQ1,(unsigned)(t+1), SEQ2,(unsigned)(t+1),64, nullptr,0u);
    }
    __syncthreads();
    const size_t sl = BIG ? (size_t)t : (size_t)(t&7);
    const u16* h0c = H0 + sl*S0;
    const u16* h1c = H1 + sl*S12;
    const u16* h2c = H2 + sl*S12;
    f32x4 sa[12], sb[12];
    f32x4 acc0={0,0,0,0}, acc1={0,0,0,0};
    asm volatile("s_nop 1" : "+v"(acc0), "+v"(acc1));
    P_ISS(0,0); P_ISS(6,6);
    WAITV(12); P_MM(0,0);  P_ISS(0,12);
    WAITV(12); P_MM(6,6);  P_ISS(6,18);
    WAITV(12); P_MM(0,12);
    WAITV(0);  P_MM(6,18);
    asm volatile("s_nop 7\n\ts_nop 7" : "+v"(acc0), "+v"(acc1));
    #pragma unroll
    for (int i=0;i<4;i++){ red[w][0][0][(ln<<2)+i]=acc0[i]; red[w][0][1][(ln<<2)+i]=acc1[i]; }
    __syncthreads();
    if constexpr (!BIG){ if (tid==0) st_b32_sc(SEQ3+jt, (unsigned)(t+1)); }
    if (t >= wash){
      float v=0.f;
      #pragma unroll
      for (int ww=0;ww<8;ww++) v += red[ww][0][h_][pos];
      st_f32_sc(&out[(((size_t)(t-wash))*32 + b_)*128 + (jt<<4)+col_], v + bvp);
    }
    __syncthreads();
  }
  // final hidden state -> [layer][b][j] fp32
  {
    const size_t sl = BIG ? (size_t)511 : (size_t)7;
    const u16* H0s = H0 + sl*S0;
    const u16* H1s = H1 + sl*S12;
    const u16* H2s = H2 + sl*S12;
    for (int q = jt*512 + tid; q < 196608; q += 4096){
      int l = q>>16, rem = q&65535, b = rem>>11, j = rem&2047;
      const u16* h = (l==0)? H0s : ((l==1)? H1s : H2s);
      unsigned tmp;
      if constexpr (BIG)
        asm volatile("global_load_ushort %0, %1, off sc0" : "=v"(tmp) : "v"(h+frag_addr(b,j)));
      else
        asm volatile("global_load_ushort %0, %1, off sc0 sc1" : "=v"(tmp) : "v"(h+frag_addr(b,j)));
      asm volatile("s_waitcnt vmcnt(0)" ::: "memory");
      st_f32_sc(&out[1966080 + q], b2f((u16)tmp));
    }
  }
}

// ---------------- top-level persistent kernel ----------------
template<int BIG>
__global__ __launch_bounds__(512,2) void k_esn(
    const u16* __restrict__ p0, const u16* __restrict__ p1, const u16* __restrict__ p2, const u16* __restrict__ po,
    const float* __restrict__ b0, const float* __restrict__ b1, const float* __restrict__ b2, const float* __restrict__ bo,
    const float* __restrict__ input, const int* __restrict__ washp,
    u16* H0, u16* H1, u16* H2, const u16* HZ0, const u16* HZ12,
    unsigned* flags, float* out)
{
  __shared__ float red[8][2][2][256];
  __shared__ u16 ldsout[1024];
  const int bid = blockIdx.x, tid = threadIdx.x;
  unsigned* SEQ0 = flags; unsigned* SEQ1 = flags+64; unsigned* SEQ2 = flags+128; unsigned* SEQ3 = flags+192;

  if constexpr (BIG){
    // launch-time cleanse: drop replay-stale L2 lines. Safe: every store in
    // k_pack/k_esn is sc0sc1 write-through -> nothing dirty to lose.
    if (tid < 64) l2_cleanse();
    __syncthreads();
  }

  if (bid < 64)       run_l0<BIG> (p0, b0, input, H0, HZ0, SEQ0, SEQ1, SEQ3, bid*2, red, ldsout);
  else if (bid < 128) run_l12<BIG>(p1, b1, H0, S0,  H1, HZ12, SEQ0, SEQ1, SEQ2, 64, SEQ3, (bid-64)*2, red, ldsout);
  else if (bid < 192) run_l12<BIG>(p2, b2, H1, S12, H2, HZ12, SEQ1, SEQ2, SEQ3, 8, nullptr, (bid-128)*2, red, ldsout);
  else                run_proj<BIG>(po, bo, H0, H1, H2, out, washp, SEQ0, SEQ1, SEQ2, SEQ3, bid-192, red);
}

extern "C" void kernel_launch(void* const* d_in, const int* in_sizes, int n_in,
                              void* d_out, int out_size, void* d_ws, size_t ws_size,
                              hipStream_t stream)
{
  (void)in_sizes; (void)n_in; (void)out_size;
  const float* input=(const float*)d_in[0];
  const float* wih0=(const float*)d_in[1]; const float* bih0=(const float*)d_in[2];
  const float* whh0=(const float*)d_in[3];
  const float* wih1=(const float*)d_in[4]; const float* bih1=(const float*)d_in[5];
  const float* whh1=(const float*)d_in[6];
  const float* wih2=(const float*)d_in[7]; const float* bih2=(const float*)d_in[8];
  const float* whh2=(const float*)d_in[9];
  const float* wout=(const float*)d_in[10]; const float* bout=(const float*)d_in[11];
  const int* washp=(const int*)d_in[12];
  float* out=(float*)d_out;

  u16* p0=(u16*)d_ws;
  u16* p1=p0+E0P;
  u16* p2=p1+E1P;
  u16* po=p2+E1P;
  unsigned* flags=(unsigned*)(po+EPP);
  u16* HZ0=(u16*)(flags+256);
  u16* HZ12=HZ0+S0;
  u16* H0=HZ12+S12;

  // BIG layout: 512 slots each for H0/H1/H2
  size_t bigH0=(size_t)512*S0, bigH12=(size_t)512*S12;
  size_t need_big = ((size_t)(H0 - p0) + bigH0 + 2*bigH12) * sizeof(u16);
  int big = (ws_size >= need_big) ? 1 : 0;

  size_t nslot = big ? 512 : NSLOT;
  u16* H1 = H0 + nslot*S0;
  u16* H2 = H1 + nslot*S12;

  // memset: weights + flags + zero-slots (+ small path: the 8-slot region, as R12)
  size_t clr = ((size_t)(H0 - p0))*sizeof(u16);
  if (!big) clr = ((size_t)(H2 + nslot*S12 - p0))*sizeof(u16);
  hipMemsetAsync(d_ws, 0, clr, stream);
  k_pack<<<dim3(2048),dim3(256),0,stream>>>(wih0,whh0,wih1,whh1,wih2,whh2,wout,p0,p1,p2,po);

  void* args[] = { (void*)&p0, (void*)&p1, (void*)&p2, (void*)&po,
                   (void*)&bih0, (void*)&bih1, (void*)&bih2, (void*)&bout,
                   (void*)&input, (void*)&washp,
                   (void*)&H0, (void*)&H1, (void*)&H2, (void*)&HZ0, (void*)&HZ12,
                   (void*)&flags, (void*)&out };
  if (big)
    hipLaunchCooperativeKernel((const void*)k_esn<1>, dim3(200), dim3(512), args, 0, stream);
  else
    hipLaunchCooperativeKernel((const void*)k_esn<0>, dim3(200), dim3(512), args, 0, stream);
}

// Round 15
// 4055.286 us; speedup vs baseline: 1.5075x; 1.5075x over previous
//
#include <hip/hip_runtime.h>
#include <hip/hip_bf16.h>

// ESN persistent pipeline v9 = R12 + poll-storm fix.
// Theory: 200 blocks re-reading 3-4 seqno arrays (13+ cache lines) every
// ~800cy saturates hot LLC lines; all sc0sc1 data loads queue behind them.
// Deltas vs R12 (4.91ms, passed): (1) u16 seqnos -> each array = ONE 128B
// line; (2) escalating poll backoff (2 fast iters, then s_sleep(16)).
// Weights AGPR-resident via "a"-operand MFMA (R12). All else identical.

typedef unsigned short u16;
typedef __attribute__((ext_vector_type(8))) __bf16 bf16x8;
typedef __attribute__((ext_vector_type(4))) float f32x4;

#define MFMA_AG(acc, a, w) \
  asm volatile("v_mfma_f32_16x16x32_bf16 %0, %1, %2, %0" : "+v"(acc) : "v"(a), "a"(w))

#define KC0 72
#define KC1 128
#define KCP 192
#define E0P (128*KC0*512)
#define E1P (128*KC1*512)
#define EPP (8*KCP*512)
#define CH 1024                // u16 per chunk
#define S0 (68*CH)             // H0 slot: 64 h-chunks + 4 pad chunks
#define S12 (64*CH)
#define NSLOT 8

static __device__ __forceinline__ float b2f(u16 u){ return __uint_as_float(((unsigned)u)<<16); }
static __device__ __forceinline__ u16 f2b(float f){ unsigned x=__float_as_uint(f); return (u16)((x + 0x7FFFu + ((x>>16)&1u))>>16); }
static __device__ __forceinline__ int frag_addr(int b, int j){
  int c=j>>5, ko=j&31, half=b>>4, lane=(b&15)|((ko>>3)<<4), e=ko&7;
  return ((c*2+half)*64+lane)*8+e;
}
static __device__ __forceinline__ bf16x8 asbf(f32x4 v){ union U{f32x4 f; bf16x8 b;} u; u.f=v; return u.b; }

// ---- coherent primitives ----
static __device__ __forceinline__ f32x4 ld16_sc(const u16* p){
  f32x4 r;
  asm volatile("global_load_dwordx4 %0, %1, off sc0 sc1" : "=v"(r) : "v"(p));
  return r;
}
static __device__ __forceinline__ f32x4 ld16_pl(const float* p){
  f32x4 r;
  asm volatile("global_load_dwordx4 %0, %1, off" : "=v"(r) : "v"(p));
  return r;
}
static __device__ __forceinline__ void st_b128_sc(u16* p, f32x4 v){
  asm volatile("global_store_dwordx4 %0, %1, off sc0 sc1" :: "v"(p), "v"(v) : "memory");
}
static __device__ __forceinline__ void st_b16_sc(u16* p, unsigned v){
  asm volatile("global_store_short %0, %1, off sc0 sc1" :: "v"(p), "v"(v) : "memory");
}
static __device__ __forceinline__ void drain(){
  asm volatile("s_waitcnt vmcnt(0)" ::: "memory");
}
#define WAITV(n) do{ asm volatile("s_waitcnt vmcnt(" #n ")" ::: "memory"); __builtin_amdgcn_sched_barrier(0); }while(0)

// wave-parallel seqno poll: u16 entries (1 line/array), escalating backoff.
static __device__ __forceinline__ void poll4(int lane,
    const u16* a, unsigned ta,
    const u16* b, unsigned tb,
    const u16* c, unsigned tc, int nc,
    const u16* d, unsigned td)
{
  int spin = 0;
  for(;;){
    unsigned va=0, vb=0, vc=0, vd=0;
    asm volatile("global_load_ushort %0, %1, off sc0 sc1" : "=v"(va) : "v"(a+lane));
    if (b) asm volatile("global_load_ushort %0, %1, off sc0 sc1" : "=v"(vb) : "v"(b+lane));
    if (c) asm volatile("global_load_ushort %0, %1, off sc0 sc1" : "=v"(vc) : "v"(c+(lane<nc?lane:0)));
    if (d) asm volatile("global_load_ushort %0, %1, off sc0 sc1" : "=v"(vd) : "v"(d+(lane<8?lane:0)));
    asm volatile("s_waitcnt vmcnt(0)" ::: "memory");
    __builtin_amdgcn_sched_barrier(0);
    bool ok = (va>=ta);
    if (b) ok &= (vb>=tb);
    if (c) ok &= (lane>=nc) || (vc>=tc);
    if (d) ok &= (lane>=8) || (vd>=td);
    if (__all(ok)) return;
    if (spin < 2){ __builtin_amdgcn_s_sleep(1); ++spin; }
    else __builtin_amdgcn_s_sleep(16);
  }
}

// ---------------- weight pack (unchanged, verified) ----------------
__global__ __launch_bounds__(256) void k_pack(const float* __restrict__ wih0, const float* __restrict__ whh0,
    const float* __restrict__ wih1, const float* __restrict__ whh1,
    const float* __restrict__ wih2, const float* __restrict__ whh2,
    const float* __restrict__ wout,
    u16* __restrict__ p0, u16* __restrict__ p1, u16* __restrict__ p2, u16* __restrict__ po)
{
  const long SRC0 = 2048L*2176, SRC1 = 2048L*4096, SRCP = 128L*6144;
  const long total8 = (SRC0 + 2*SRC1 + SRCP) >> 3;
  for (long id = (long)blockIdx.x*blockDim.x + threadIdx.x; id < total8; id += (long)gridDim.x*blockDim.x){
    long r = id<<3; int KC, j, k; u16* dst;
    const float* sa; const float* sb; int split;
    if (r < SRC0){ KC=KC0; j=(int)(r/2176); k=(int)(r%2176); sa=wih0+(size_t)j*128; sb=whh0+(size_t)j*2048; split=128; dst=p0; }
    else if ((r -= SRC0) < SRC1){ KC=KC1; j=(int)(r/4096); k=(int)(r%4096); sa=wih1+(size_t)j*2048; sb=whh1+(size_t)j*2048; split=2048; dst=p1; }
    else if ((r -= SRC1) < SRC1){ KC=KC1; j=(int)(r/4096); k=(int)(r%4096); sa=wih2+(size_t)j*2048; sb=whh2+(size_t)j*2048; split=2048; dst=p2; }
    else { r -= SRC1; KC=KCP; j=(int)(r/6144); k=(int)(r%6144); sa=wout+(size_t)j*6144; sb=sa; split=6144; dst=po; }
    const float* src = (k<split) ? (sa + k) : (sb + (k - split));
    u16 tmp[8];
    #pragma unroll
    for (int e=0;e<8;e++) tmp[e] = f2b(src[e]);
    int jt=j>>4, jl=j&15, c=k>>5, ko=k&31, lane=((ko>>3)<<4)|jl;
    u16* dp = dst + (((size_t)jt*KC + c)*64 + lane)*8;
    *(f32x4*)dp = *(f32x4*)tmp;
  }
}

// ---- L12 rolling staging: 8 slots, 16 chunks ----
#define L12_ISS(s0, c0) \
  _Pragma("unroll") \
  for (int i=0;i<4;++i){ \
    sa[(s0)+i]=ld16_sc(apb + (size_t)((c0)+i)*CH); \
    sb[(s0)+i]=ld16_sc(apb + (size_t)((c0)+i)*CH + 512); \
  }
#define L12_MM(s0, c0) \
  _Pragma("unroll") \
  for (int i=0;i<4;++i){ \
    bf16x8 a0=asbf(sa[(s0)+i]), a1=asbf(sb[(s0)+i]); \
    MFMA_AG(acc00,a0,wreg[0][(c0)+i]); MFMA_AG(acc01,a1,wreg[0][(c0)+i]); \
    MFMA_AG(acc10,a0,wreg[1][(c0)+i]); MFMA_AG(acc11,a1,wreg[1][(c0)+i]); \
  }
#define PIN_ACC4() asm volatile("s_nop 1" : "+v"(acc00), "+v"(acc01), "+v"(acc10), "+v"(acc11))
#define FENCE_ACC4() asm volatile("s_nop 7\n\ts_nop 7" : "+v"(acc00), "+v"(acc01), "+v"(acc10), "+v"(acc11))

// ---------------- layer 1/2 persistent loop ----------------
static __device__ __forceinline__ void run_l12(
    const u16* __restrict__ pW, const float* __restrict__ bias,
    const u16* __restrict__ A0slots, size_t a0stride, u16* OWN,
    u16* SEQup, u16* SEQown, u16* Sc, int nc, u16* Sd,
    int jt0, float (*red)[2][2][256], u16* ldsout)
{
  const int tid=threadIdx.x, w=tid>>6, ln=tid&63;
  bf16x8 wreg[2][16];            // -> AGPRs
  #pragma unroll
  for (int u=0;u<2;u++)
    #pragma unroll
    for (int ci=0;ci<16;ci++)
      wreg[u][ci] = *(const bf16x8*)(pW + (((size_t)(jt0+u)*KC1 + (w*16+ci))*64 + ln)*8);

  const int h_=tid>>8, pos=tid&255, l_=pos>>2, i_=pos&3, col_=l_&15, row_=((l_>>4)<<2)+i_, b_=(h_<<4)+row_;
  const float bv0=bias[(jt0<<4)+col_], bv1=bias[((jt0+1)<<4)+col_];
  const int ko0=col_, ko1=16+col_;
  const int faw0=((h_*64)+((b_&15)|((ko0>>3)<<4)))*8+(ko0&7);
  const int faw1=((h_*64)+((b_&15)|((ko1>>3)<<4)))*8+(ko1&7);
  const int myc=jt0>>1, gidx=jt0>>1;

  if (tid<128) *(f32x4*)(ldsout+tid*8) = (f32x4){0,0,0,0};
  __syncthreads();

  for (int t=0;t<512;t++){
    if (tid<64){
      poll4(tid, SEQup,(unsigned)(t+1), SEQown,(unsigned)t,
            (t>=NSLOT)?Sc:nullptr,(unsigned)(t-7),nc,
            (t>=NSLOT)?Sd:nullptr,(unsigned)(t-7));
    }
    __syncthreads();
    const int cur=t&7, prv=(t+7)&7;
    const u16* a0base = (w<4) ? A0slots + (size_t)cur*a0stride + (size_t)(w*16)*CH
                              : OWN + (size_t)prv*S12 + (size_t)((w-4)*16)*CH;
    const u16* apb = a0base + (size_t)ln*8;
    f32x4 sa[8], sb[8];
    f32x4 acc00={0,0,0,0},acc01={0,0,0,0},acc10={0,0,0,0},acc11={0,0,0,0};
    PIN_ACC4();
    L12_ISS(0,0); L12_ISS(4,4);
    WAITV(8); L12_MM(0,0); L12_ISS(0,8);
    WAITV(8); L12_MM(4,4); L12_ISS(4,12);
    WAITV(8); L12_MM(0,8);
    WAITV(0); L12_MM(4,12);
    FENCE_ACC4();
    #pragma unroll
    for (int i=0;i<4;i++){
      red[w][0][0][(ln<<2)+i]=acc00[i]; red[w][0][1][(ln<<2)+i]=acc01[i];
      red[w][1][0][(ln<<2)+i]=acc10[i]; red[w][1][1][(ln<<2)+i]=acc11[i];
    }
    __syncthreads();
    {
      float v0=0.f, v1=0.f;
      #pragma unroll
      for (int ww=0;ww<8;ww++){ v0 += red[ww][0][h_][pos]; v1 += red[ww][1][h_][pos]; }
      float hp0 = b2f(ldsout[faw0]);
      float hp1 = b2f(ldsout[faw1]);
      ldsout[faw0] = f2b(0.05f*hp0 + 0.95f*tanhf(v0 + bv0));
      ldsout[faw1] = f2b(0.05f*hp1 + 0.95f*tanhf(v1 + bv1));
    }
    __syncthreads();
    if (tid<128){
      f32x4 vv = *(const f32x4*)(ldsout + tid*8);
      st_b128_sc(OWN + (size_t)cur*S12 + (size_t)myc*CH + tid*8, vv);
    }
    drain();
    __syncthreads();
    if (tid==0) st_b16_sc(SEQown+gidx, (unsigned)(t+1));
  }
}

// ---- L0 staged-load macros ----
#define X_ISSUE(ci) do{ \
    const float* q0 = xf + rr*128 + (ci)*32 + kg*8; \
    xs0[ci]=ld16_pl(q0); xs1[ci]=ld16_pl(q0+4); \
    xs2[ci]=ld16_pl(q0+2048); xs3[ci]=ld16_pl(q0+2052); \
  }while(0)
#define X_MFMA(ci) do{ \
    bf16x8 a0,a1; \
    _Pragma("unroll") \
    for (int e=0;e<4;e++){ a0[e]=(__bf16)xs0[ci][e]; a0[e+4]=(__bf16)xs1[ci][e]; \
                           a1[e]=(__bf16)xs2[ci][e]; a1[e+4]=(__bf16)xs3[ci][e]; } \
    asm volatile("s_nop 1" : "+v"(a0), "+v"(a1)); \
    MFMA_AG(acc00,a0,wreg[0][ci]); MFMA_AG(acc01,a1,wreg[0][ci]); \
    MFMA_AG(acc10,a0,wreg[1][ci]); MFMA_AG(acc11,a1,wreg[1][ci]); \
  }while(0)
#define LH_ISSUE(ci) do{ sa[ci]=ld16_sc(hbp + (size_t)(ci)*CH); sb[ci]=ld16_sc(hbp + (size_t)(ci)*CH + 512); }while(0)
#define LH_MFMA(ci) do{ \
    bf16x8 a0=asbf(sa[ci]), a1=asbf(sb[ci]); \
    MFMA_AG(acc00,a0,wreg[0][ci]); MFMA_AG(acc01,a1,wreg[0][ci]); \
    MFMA_AG(acc10,a0,wreg[1][ci]); MFMA_AG(acc11,a1,wreg[1][ci]); \
  }while(0)

// ---------------- layer 0 persistent loop ----------------
static __device__ __forceinline__ void run_l0(
    const u16* __restrict__ pW, const float* __restrict__ bias, const float* __restrict__ input,
    u16* H0, u16* SEQ0, u16* SEQ1, u16* SEQ3,
    int jt0, float (*red)[2][2][256], u16* ldsout)
{
  const int tid=threadIdx.x, w=tid>>6, ln=tid&63, rr=ln&15, kg=ln>>4;
  bf16x8 wreg[2][9];             // -> AGPRs
  #pragma unroll
  for (int u=0;u<2;u++)
    #pragma unroll
    for (int ci=0;ci<9;ci++)
      wreg[u][ci] = *(const bf16x8*)(pW + (((size_t)(jt0+u)*KC0 + (w*9+ci))*64 + ln)*8);

  const int h_=tid>>8, pos=tid&255, l_=pos>>2, i_=pos&3, col_=l_&15, row_=((l_>>4)<<2)+i_, b_=(h_<<4)+row_;
  const float bv0=bias[(jt0<<4)+col_], bv1=bias[((jt0+1)<<4)+col_];
  const int ko0=col_, ko1=16+col_;
  const int faw0=((h_*64)+((b_&15)|((ko0>>3)<<4)))*8+(ko0&7);
  const int faw1=((h_*64)+((b_&15)|((ko1>>3)<<4)))*8+(ko1&7);
  const int myc=jt0>>1, gidx=jt0>>1;

  if (tid<128) *(f32x4*)(ldsout+tid*8) = (f32x4){0,0,0,0};
  __syncthreads();

  for (int t=0;t<512;t++){
    if (tid<64){
      poll4(tid, SEQ0,(unsigned)t, (t>=NSLOT)?SEQ1:nullptr,(unsigned)(t-7),
            (t>=NSLOT)?SEQ3:nullptr,(unsigned)(t-7),8, nullptr,0u);
    }
    __syncthreads();
    const int cur=t&7, prv=(t+7)&7;
    const float* xf = input + (size_t)t*4096;
    const u16* h0prv = H0 + (size_t)prv*S0;
    f32x4 acc00={0,0,0,0},acc01={0,0,0,0},acc10={0,0,0,0},acc11={0,0,0,0};
    PIN_ACC4();
    if (w==0){
      f32x4 xs0[4],xs1[4],xs2[4],xs3[4], sa[9], sb[9];
      const u16* hbp = h0prv - (size_t)4*CH + (size_t)ln*8;  // deref only at ci>=4
      X_ISSUE(0); X_ISSUE(1);
      X_ISSUE(2); X_ISSUE(3); WAITV(8); X_MFMA(0); X_MFMA(1);
      LH_ISSUE(4); LH_ISSUE(5); LH_ISSUE(6); LH_ISSUE(7); LH_ISSUE(8);
      WAITV(10); X_MFMA(2); X_MFMA(3);
      WAITV(0);
      LH_MFMA(4); LH_MFMA(5); LH_MFMA(6); LH_MFMA(7); LH_MFMA(8);
    } else {
      f32x4 sa[9], sb[9];
      const u16* hbp = h0prv + (size_t)(w*9-4)*CH + (size_t)ln*8;
      LH_ISSUE(0); LH_ISSUE(1); LH_ISSUE(2); LH_ISSUE(3);
      LH_ISSUE(4); LH_ISSUE(5); LH_ISSUE(6); LH_ISSUE(7);
      WAITV(8);  LH_MFMA(0); LH_MFMA(1); LH_MFMA(2); LH_MFMA(3);
      LH_ISSUE(8);
      WAITV(2);  LH_MFMA(4); LH_MFMA(5); LH_MFMA(6); LH_MFMA(7);
      WAITV(0);  LH_MFMA(8);
    }
    FENCE_ACC4();
    #pragma unroll
    for (int i=0;i<4;i++){
      red[w][0][0][(ln<<2)+i]=acc00[i]; red[w][0][1][(ln<<2)+i]=acc01[i];
      red[w][1][0][(ln<<2)+i]=acc10[i]; red[w][1][1][(ln<<2)+i]=acc11[i];
    }
    __syncthreads();
    {
      float v0=0.f, v1=0.f;
      #pragma unroll
      for (int ww=0;ww<8;ww++){ v0 += red[ww][0][h_][pos]; v1 += red[ww][1][h_][pos]; }
      float hp0 = b2f(ldsout[faw0]);
      float hp1 = b2f(ldsout[faw1]);
      ldsout[faw0] = f2b(0.05f*hp0 + 0.95f*tanhf(v0 + bv0));
      ldsout[faw1] = f2b(0.05f*hp1 + 0.95f*tanhf(v1 + bv1));
    }
    __syncthreads();
    if (tid<128){
      f32x4 vv = *(const f32x4*)(ldsout + tid*8);
      st_b128_sc(H0 + (size_t)cur*S0 + (size_t)myc*CH + tid*8, vv);
    }
    drain();
    __syncthreads();
    if (tid==0) st_b16_sc(SEQ0+gidx, (unsigned)(t+1));
  }
}

// ---- proj rolling staging: 12 slots, 24 chunks ----
#define P_AP(kc_) ((kc_)<64 ? h0c+(size_t)(kc_)*CH : ((kc_)<128 ? h1c+(size_t)((kc_)-64)*CH : h2c+(size_t)((kc_)-128)*CH))
#define P_ISS(s0, c0) \
  _Pragma("unroll") \
  for (int i=0;i<6;++i){ \
    const u16* ap = P_AP(w*24+(c0)+i) + (size_t)ln*8; \
    sa[(s0)+i]=ld16_sc(ap); sb[(s0)+i]=ld16_sc(ap+512); \
  }
#define P_MM(s0, c0) \
  _Pragma("unroll") \
  for (int i=0;i<6;++i){ \
    bf16x8 a0=asbf(sa[(s0)+i]), a1=asbf(sb[(s0)+i]); \
    MFMA_AG(acc0,a0,wreg[(c0)+i]); MFMA_AG(acc1,a1,wreg[(c0)+i]); \
  }

// ---------------- projection persistent loop + final-h epilogue ----------------
static __device__ __forceinline__ void run_proj(
    const u16* __restrict__ pW, const float* __restrict__ bo,
    const u16* __restrict__ H0, const u16* __restrict__ H1, const u16* __restrict__ H2,
    float* __restrict__ out, const int* __restrict__ washp,
    u16* SEQ0, u16* SEQ1, u16* SEQ2, u16* SEQ3,
    int jt, float (*red)[2][2][256])
{
  const int tid=threadIdx.x, w=tid>>6, ln=tid&63;
  bf16x8 wreg[24];               // -> AGPRs
  #pragma unroll
  for (int ci=0;ci<24;ci++)
    wreg[ci] = *(const bf16x8*)(pW + (((size_t)jt*KCP + (w*24+ci))*64 + ln)*8);
  const int wash = *washp;
  const int h_=tid>>8, pos=tid&255, l_=pos>>2, i_=pos&3, col_=l_&15, row_=((l_>>4)<<2)+i_, b_=(h_<<4)+row_;
  const float bvp = bo[(jt<<4)+col_];

  for (int t=0;t<512;t++){
    if (tid<64){
      poll4(tid, SEQ0,(unsigned)(t+1), SEQ1,(unsigned)(t+1), SEQ2,(unsigned)(t+1),64, nullptr,0u);
    }
    __syncthreads();
    const int cur=t&7;
    const u16* h0c = H0 + (size_t)cur*S0;
    const u16* h1c = H1 + (size_t)cur*S12;
    const u16* h2c = H2 + (size_t)cur*S12;
    f32x4 sa[12], sb[12];
    f32x4 acc0={0,0,0,0}, acc1={0,0,0,0};
    asm volatile("s_nop 1" : "+v"(acc0), "+v"(acc1));
    P_ISS(0,0); P_ISS(6,6);
    WAITV(12); P_MM(0,0);  P_ISS(0,12);
    WAITV(12); P_MM(6,6);  P_ISS(6,18);
    WAITV(12); P_MM(0,12);
    WAITV(0);  P_MM(6,18);
    asm volatile("s_nop 7\n\ts_nop 7" : "+v"(acc0), "+v"(acc1));
    #pragma unroll
    for (int i=0;i<4;i++){ red[w][0][0][(ln<<2)+i]=acc0[i]; red[w][0][1][(ln<<2)+i]=acc1[i]; }
    __syncthreads();
    if (tid==0) st_b16_sc(SEQ3+jt, (unsigned)(t+1));   // reads of slot done
    if (t >= wash){
      float v=0.f;
      #pragma unroll
      for (int ww=0;ww<8;ww++) v += red[ww][0][h_][pos];
      out[(((size_t)(t-wash))*32 + b_)*128 + (jt<<4)+col_] = v + bvp;
    }
    __syncthreads();
  }
  // final hidden state: slot 7, frag layout -> [layer][b][j] fp32
  for (int q = jt*512 + tid; q < 196608; q += 4096){
    int l = q>>16, rem = q&65535, b = rem>>11, j = rem&2047;
    const u16* h = (l==0)? H0+(size_t)7*S0 : ((l==1)? H1+(size_t)7*S12 : H2+(size_t)7*S12);
    out[1966080 + q] = b2f(h[frag_addr(b,j)]);
  }
}

// ---------------- top-level persistent kernel ----------------
__global__ __launch_bounds__(512,2) void k_esn(
    const u16* __restrict__ p0, const u16* __restrict__ p1, const u16* __restrict__ p2, const u16* __restrict__ po,
    const float* __restrict__ b0, const float* __restrict__ b1, const float* __restrict__ b2, const float* __restrict__ bo,
    const float* __restrict__ input, const int* __restrict__ washp,
    u16* H0, u16* H1, u16* H2, u16* flags, float* out)
{
  __shared__ float red[8][2][2][256];
  __shared__ u16 ldsout[1024];
  const int bid = blockIdx.x;
  u16* SEQ0 = flags; u16* SEQ1 = flags+64; u16* SEQ2 = flags+128; u16* SEQ3 = flags+192;

  if (bid < 64)       run_l0 (p0, b0, input, H0, SEQ0, SEQ1, SEQ3, bid*2, red, ldsout);
  else if (bid < 128) run_l12(p1, b1, H0, S0,  H1, SEQ0, SEQ1, SEQ2, 64, SEQ3, (bid-64)*2, red, ldsout);
  else if (bid < 192) run_l12(p2, b2, H1, S12, H2, SEQ1, SEQ2, SEQ3, 8, nullptr, (bid-128)*2, red, ldsout);
  else                run_proj(po, bo, H0, H1, H2, out, washp, SEQ0, SEQ1, SEQ2, SEQ3, bid-192, red);
}

extern "C" void kernel_launch(void* const* d_in, const int* in_sizes, int n_in,
                              void* d_out, int out_size, void* d_ws, size_t ws_size,
                              hipStream_t stream)
{
  (void)in_sizes; (void)n_in; (void)out_size; (void)ws_size;
  const float* input=(const float*)d_in[0];
  const float* wih0=(const float*)d_in[1]; const float* bih0=(const float*)d_in[2];
  const float* whh0=(const float*)d_in[3];
  const float* wih1=(const float*)d_in[4]; const float* bih1=(const float*)d_in[5];
  const float* whh1=(const float*)d_in[6];
  const float* wih2=(const float*)d_in[7]; const float* bih2=(const float*)d_in[8];
  const float* whh2=(const float*)d_in[9];
  const float* wout=(const float*)d_in[10]; const float* bout=(const float*)d_in[11];
  const int* washp=(const int*)d_in[12];
  float* out=(float*)d_out;

  u16* p0=(u16*)d_ws;
  u16* p1=p0+E0P;
  u16* p2=p1+E1P;
  u16* po=p2+E1P;
  u16* H0=po+EPP;
  u16* H1=H0+(size_t)NSLOT*S0;
  u16* H2=H1+(size_t)NSLOT*S12;
  u16* flags=H2+(size_t)NSLOT*S12;   // 256 u16 seqnos (4 x 128B lines)
  size_t totbytes = ((char*)(flags+256)) - ((char*)d_ws);

  hipMemsetAsync(d_ws, 0, totbytes, stream);
  k_pack<<<dim3(2048),dim3(256),0,stream>>>(wih0,whh0,wih1,whh1,wih2,whh2,wout,p0,p1,p2,po);

  void* args[] = { (void*)&p0, (void*)&p1, (void*)&p2, (void*)&po,
                   (void*)&bih0, (void*)&bih1, (void*)&bih2, (void*)&bout,
                   (void*)&input, (void*)&washp,
                   (void*)&H0, (void*)&H1, (void*)&H2, (void*)&flags, (void*)&out };
  hipLaunchCooperativeKernel((const void*)k_esn, dim3(200), dim3(512), args, 0, stream);
}

// Round 17
// 4027.142 us; speedup vs baseline: 1.5180x; 1.0070x over previous
//
#include <hip/hip_runtime.h>
#include <hip/hip_bf16.h>

// ESN persistent pipeline v9.1 = R15 (4.06ms, passed) with poll backoff
// s_sleep(16) -> s_sleep(8). Everything else byte-identical.
// R15 design: weights AGPR-resident ("a"-operand MFMA), rolling vmcnt-staged
// sc0sc1 coherent loads, u16 single-line seqno arrays, escalating backoff.

typedef unsigned short u16;
typedef __attribute__((ext_vector_type(8))) __bf16 bf16x8;
typedef __attribute__((ext_vector_type(4))) float f32x4;

#define MFMA_AG(acc, a, w) \
  asm volatile("v_mfma_f32_16x16x32_bf16 %0, %1, %2, %0" : "+v"(acc) : "v"(a), "a"(w))

#define KC0 72
#define KC1 128
#define KCP 192
#define E0P (128*KC0*512)
#define E1P (128*KC1*512)
#define EPP (8*KCP*512)
#define CH 1024                // u16 per chunk
#define S0 (68*CH)             // H0 slot: 64 h-chunks + 4 pad chunks
#define S12 (64*CH)
#define NSLOT 8

static __device__ __forceinline__ float b2f(u16 u){ return __uint_as_float(((unsigned)u)<<16); }
static __device__ __forceinline__ u16 f2b(float f){ unsigned x=__float_as_uint(f); return (u16)((x + 0x7FFFu + ((x>>16)&1u))>>16); }
static __device__ __forceinline__ int frag_addr(int b, int j){
  int c=j>>5, ko=j&31, half=b>>4, lane=(b&15)|((ko>>3)<<4), e=ko&7;
  return ((c*2+half)*64+lane)*8+e;
}
static __device__ __forceinline__ bf16x8 asbf(f32x4 v){ union U{f32x4 f; bf16x8 b;} u; u.f=v; return u.b; }

// ---- coherent primitives ----
static __device__ __forceinline__ f32x4 ld16_sc(const u16* p){
  f32x4 r;
  asm volatile("global_load_dwordx4 %0, %1, off sc0 sc1" : "=v"(r) : "v"(p));
  return r;
}
static __device__ __forceinline__ f32x4 ld16_pl(const float* p){
  f32x4 r;
  asm volatile("global_load_dwordx4 %0, %1, off" : "=v"(r) : "v"(p));
  return r;
}
static __device__ __forceinline__ void st_b128_sc(u16* p, f32x4 v){
  asm volatile("global_store_dwordx4 %0, %1, off sc0 sc1" :: "v"(p), "v"(v) : "memory");
}
static __device__ __forceinline__ void st_b16_sc(u16* p, unsigned v){
  asm volatile("global_store_short %0, %1, off sc0 sc1" :: "v"(p), "v"(v) : "memory");
}
static __device__ __forceinline__ void drain(){
  asm volatile("s_waitcnt vmcnt(0)" ::: "memory");
}
#define WAITV(n) do{ asm volatile("s_waitcnt vmcnt(" #n ")" ::: "memory"); __builtin_amdgcn_sched_barrier(0); }while(0)

// wave-parallel seqno poll: u16 entries (1 line/array), escalating backoff.
static __device__ __forceinline__ void poll4(int lane,
    const u16* a, unsigned ta,
    const u16* b, unsigned tb,
    const u16* c, unsigned tc, int nc,
    const u16* d, unsigned td)
{
  int spin = 0;
  for(;;){
    unsigned va=0, vb=0, vc=0, vd=0;
    asm volatile("global_load_ushort %0, %1, off sc0 sc1" : "=v"(va) : "v"(a+lane));
    if (b) asm volatile("global_load_ushort %0, %1, off sc0 sc1" : "=v"(vb) : "v"(b+lane));
    if (c) asm volatile("global_load_ushort %0, %1, off sc0 sc1" : "=v"(vc) : "v"(c+(lane<nc?lane:0)));
    if (d) asm volatile("global_load_ushort %0, %1, off sc0 sc1" : "=v"(vd) : "v"(d+(lane<8?lane:0)));
    asm volatile("s_waitcnt vmcnt(0)" ::: "memory");
    __builtin_amdgcn_sched_barrier(0);
    bool ok = (va>=ta);
    if (b) ok &= (vb>=tb);
    if (c) ok &= (lane>=nc) || (vc>=tc);
    if (d) ok &= (lane>=8) || (vd>=td);
    if (__all(ok)) return;
    if (spin < 2){ __builtin_amdgcn_s_sleep(1); ++spin; }
    else __builtin_amdgcn_s_sleep(8);
  }
}

// ---------------- weight pack (unchanged, verified) ----------------
__global__ __launch_bounds__(256) void k_pack(const float* __restrict__ wih0, const float* __restrict__ whh0,
    const float* __restrict__ wih1, const float* __restrict__ whh1,
    const float* __restrict__ wih2, const float* __restrict__ whh2,
    const float* __restrict__ wout,
    u16* __restrict__ p0, u16* __restrict__ p1, u16* __restrict__ p2, u16* __restrict__ po)
{
  const long SRC0 = 2048L*2176, SRC1 = 2048L*4096, SRCP = 128L*6144;
  const long total8 = (SRC0 + 2*SRC1 + SRCP) >> 3;
  for (long id = (long)blockIdx.x*blockDim.x + threadIdx.x; id < total8; id += (long)gridDim.x*blockDim.x){
    long r = id<<3; int KC, j, k; u16* dst;
    const float* sa; const float* sb; int split;
    if (r < SRC0){ KC=KC0; j=(int)(r/2176); k=(int)(r%2176); sa=wih0+(size_t)j*128; sb=whh0+(size_t)j*2048; split=128; dst=p0; }
    else if ((r -= SRC0) < SRC1){ KC=KC1; j=(int)(r/4096); k=(int)(r%4096); sa=wih1+(size_t)j*2048; sb=whh1+(size_t)j*2048; split=2048; dst=p1; }
    else if ((r -= SRC1) < SRC1){ KC=KC1; j=(int)(r/4096); k=(int)(r%4096); sa=wih2+(size_t)j*2048; sb=whh2+(size_t)j*2048; split=2048; dst=p2; }
    else { r -= SRC1; KC=KCP; j=(int)(r/6144); k=(int)(r%6144); sa=wout+(size_t)j*6144; sb=sa; split=6144; dst=po; }
    const float* src = (k<split) ? (sa + k) : (sb + (k - split));
    u16 tmp[8];
    #pragma unroll
    for (int e=0;e<8;e++) tmp[e] = f2b(src[e]);
    int jt=j>>4, jl=j&15, c=k>>5, ko=k&31, lane=((ko>>3)<<4)|jl;
    u16* dp = dst + (((size_t)jt*KC + c)*64 + lane)*8;
    *(f32x4*)dp = *(f32x4*)tmp;
  }
}

// ---- L12 rolling staging: 8 slots, 16 chunks ----
#define L12_ISS(s0, c0) \
  _Pragma("unroll") \
  for (int i=0;i<4;++i){ \
    sa[(s0)+i]=ld16_sc(apb + (size_t)((c0)+i)*CH); \
    sb[(s0)+i]=ld16_sc(apb + (size_t)((c0)+i)*CH + 512); \
  }
#define L12_MM(s0, c0) \
  _Pragma("unroll") \
  for (int i=0;i<4;++i){ \
    bf16x8 a0=asbf(sa[(s0)+i]), a1=asbf(sb[(s0)+i]); \
    MFMA_AG(acc00,a0,wreg[0][(c0)+i]); MFMA_AG(acc01,a1,wreg[0][(c0)+i]); \
    MFMA_AG(acc10,a0,wreg[1][(c0)+i]); MFMA_AG(acc11,a1,wreg[1][(c0)+i]); \
  }
#define PIN_ACC4() asm volatile("s_nop 1" : "+v"(acc00), "+v"(acc01), "+v"(acc10), "+v"(acc11))
#define FENCE_ACC4() asm volatile("s_nop 7\n\ts_nop 7" : "+v"(acc00), "+v"(acc01), "+v"(acc10), "+v"(acc11))

// ---------------- layer 1/2 persistent loop ----------------
static __device__ __forceinline__ void run_l12(
    const u16* __restrict__ pW, const float* __restrict__ bias,
    const u16* __restrict__ A0slots, size_t a0stride, u16* OWN,
    u16* SEQup, u16* SEQown, u16* Sc, int nc, u16* Sd,
    int jt0, float (*red)[2][2][256], u16* ldsout)
{
  const int tid=threadIdx.x, w=tid>>6, ln=tid&63;
  bf16x8 wreg[2][16];            // -> AGPRs
  #pragma unroll
  for (int u=0;u<2;u++)
    #pragma unroll
    for (int ci=0;ci<16;ci++)
      wreg[u][ci] = *(const bf16x8*)(pW + (((size_t)(jt0+u)*KC1 + (w*16+ci))*64 + ln)*8);

  const int h_=tid>>8, pos=tid&255, l_=pos>>2, i_=pos&3, col_=l_&15, row_=((l_>>4)<<2)+i_, b_=(h_<<4)+row_;
  const float bv0=bias[(jt0<<4)+col_], bv1=bias[((jt0+1)<<4)+col_];
  const int ko0=col_, ko1=16+col_;
  const int faw0=((h_*64)+((b_&15)|((ko0>>3)<<4)))*8+(ko0&7);
  const int faw1=((h_*64)+((b_&15)|((ko1>>3)<<4)))*8+(ko1&7);
  const int myc=jt0>>1, gidx=jt0>>1;

  if (tid<128) *(f32x4*)(ldsout+tid*8) = (f32x4){0,0,0,0};
  __syncthreads();

  for (int t=0;t<512;t++){
    if (tid<64){
      poll4(tid, SEQup,(unsigned)(t+1), SEQown,(unsigned)t,
            (t>=NSLOT)?Sc:nullptr,(unsigned)(t-7),nc,
            (t>=NSLOT)?Sd:nullptr,(unsigned)(t-7));
    }
    __syncthreads();
    const int cur=t&7, prv=(t+7)&7;
    const u16* a0base = (w<4) ? A0slots + (size_t)cur*a0stride + (size_t)(w*16)*CH
                              : OWN + (size_t)prv*S12 + (size_t)((w-4)*16)*CH;
    const u16* apb = a0base + (size_t)ln*8;
    f32x4 sa[8], sb[8];
    f32x4 acc00={0,0,0,0},acc01={0,0,0,0},acc10={0,0,0,0},acc11={0,0,0,0};
    PIN_ACC4();
    L12_ISS(0,0); L12_ISS(4,4);
    WAITV(8); L12_MM(0,0); L12_ISS(0,8);
    WAITV(8); L12_MM(4,4); L12_ISS(4,12);
    WAITV(8); L12_MM(0,8);
    WAITV(0); L12_MM(4,12);
    FENCE_ACC4();
    #pragma unroll
    for (int i=0;i<4;i++){
      red[w][0][0][(ln<<2)+i]=acc00[i]; red[w][0][1][(ln<<2)+i]=acc01[i];
      red[w][1][0][(ln<<2)+i]=acc10[i]; red[w][1][1][(ln<<2)+i]=acc11[i];
    }
    __syncthreads();
    {
      float v0=0.f, v1=0.f;
      #pragma unroll
      for (int ww=0;ww<8;ww++){ v0 += red[ww][0][h_][pos]; v1 += red[ww][1][h_][pos]; }
      float hp0 = b2f(ldsout[faw0]);
      float hp1 = b2f(ldsout[faw1]);
      ldsout[faw0] = f2b(0.05f*hp0 + 0.95f*tanhf(v0 + bv0));
      ldsout[faw1] = f2b(0.05f*hp1 + 0.95f*tanhf(v1 + bv1));
    }
    __syncthreads();
    if (tid<128){
      f32x4 vv = *(const f32x4*)(ldsout + tid*8);
      st_b128_sc(OWN + (size_t)cur*S12 + (size_t)myc*CH + tid*8, vv);
    }
    drain();
    __syncthreads();
    if (tid==0) st_b16_sc(SEQown+gidx, (unsigned)(t+1));
  }
}

// ---- L0 staged-load macros ----
#define X_ISSUE(ci) do{ \
    const float* q0 = xf + rr*128 + (ci)*32 + kg*8; \
    xs0[ci]=ld16_pl(q0); xs1[ci]=ld16_pl(q0+4); \
    xs2[ci]=ld16_pl(q0+2048); xs3[ci]=ld16_pl(q0+2052); \
  }while(0)
#define X_MFMA(ci) do{ \
    bf16x8 a0,a1; \
    _Pragma("unroll") \
    for (int e=0;e<4;e++){ a0[e]=(__bf16)xs0[ci][e]; a0[e+4]=(__bf16)xs1[ci][e]; \
                           a1[e]=(__bf16)xs2[ci][e]; a1[e+4]=(__bf16)xs3[ci][e]; } \
    asm volatile("s_nop 1" : "+v"(a0), "+v"(a1)); \
    MFMA_AG(acc00,a0,wreg[0][ci]); MFMA_AG(acc01,a1,wreg[0][ci]); \
    MFMA_AG(acc10,a0,wreg[1][ci]); MFMA_AG(acc11,a1,wreg[1][ci]); \
  }while(0)
#define LH_ISSUE(ci) do{ sa[ci]=ld16_sc(hbp + (size_t)(ci)*CH); sb[ci]=ld16_sc(hbp + (size_t)(ci)*CH + 512); }while(0)
#define LH_MFMA(ci) do{ \
    bf16x8 a0=asbf(sa[ci]), a1=asbf(sb[ci]); \
    MFMA_AG(acc00,a0,wreg[0][ci]); MFMA_AG(acc01,a1,wreg[0][ci]); \
    MFMA_AG(acc10,a0,wreg[1][ci]); MFMA_AG(acc11,a1,wreg[1][ci]); \
  }while(0)

// ---------------- layer 0 persistent loop ----------------
static __device__ __forceinline__ void run_l0(
    const u16* __restrict__ pW, const float* __restrict__ bias, const float* __restrict__ input,
    u16* H0, u16* SEQ0, u16* SEQ1, u16* SEQ3,
    int jt0, float (*red)[2][2][256], u16* ldsout)
{
  const int tid=threadIdx.x, w=tid>>6, ln=tid&63, rr=ln&15, kg=ln>>4;
  bf16x8 wreg[2][9];             // -> AGPRs
  #pragma unroll
  for (int u=0;u<2;u++)
    #pragma unroll
    for (int ci=0;ci<9;ci++)
      wreg[u][ci] = *(const bf16x8*)(pW + (((size_t)(jt0+u)*KC0 + (w*9+ci))*64 + ln)*8);

  const int h_=tid>>8, pos=tid&255, l_=pos>>2, i_=pos&3, col_=l_&15, row_=((l_>>4)<<2)+i_, b_=(h_<<4)+row_;
  const float bv0=bias[(jt0<<4)+col_], bv1=bias[((jt0+1)<<4)+col_];
  const int ko0=col_, ko1=16+col_;
  const int faw0=((h_*64)+((b_&15)|((ko0>>3)<<4)))*8+(ko0&7);
  const int faw1=((h_*64)+((b_&15)|((ko1>>3)<<4)))*8+(ko1&7);
  const int myc=jt0>>1, gidx=jt0>>1;

  if (tid<128) *(f32x4*)(ldsout+tid*8) = (f32x4){0,0,0,0};
  __syncthreads();

  for (int t=0;t<512;t++){
    if (tid<64){
      poll4(tid, SEQ0,(unsigned)t, (t>=NSLOT)?SEQ1:nullptr,(unsigned)(t-7),
            (t>=NSLOT)?SEQ3:nullptr,(unsigned)(t-7),8, nullptr,0u);
    }
    __syncthreads();
    const int cur=t&7, prv=(t+7)&7;
    const float* xf = input + (size_t)t*4096;
    const u16* h0prv = H0 + (size_t)prv*S0;
    f32x4 acc00={0,0,0,0},acc01={0,0,0,0},acc10={0,0,0,0},acc11={0,0,0,0};
    PIN_ACC4();
    if (w==0){
      f32x4 xs0[4],xs1[4],xs2[4],xs3[4], sa[9], sb[9];
      const u16* hbp = h0prv - (size_t)4*CH + (size_t)ln*8;  // deref only at ci>=4
      X_ISSUE(0); X_ISSUE(1);
      X_ISSUE(2); X_ISSUE(3); WAITV(8); X_MFMA(0); X_MFMA(1);
      LH_ISSUE(4); LH_ISSUE(5); LH_ISSUE(6); LH_ISSUE(7); LH_ISSUE(8);
      WAITV(10); X_MFMA(2); X_MFMA(3);
      WAITV(0);
      LH_MFMA(4); LH_MFMA(5); LH_MFMA(6); LH_MFMA(7); LH_MFMA(8);
    } else {
      f32x4 sa[9], sb[9];
      const u16* hbp = h0prv + (size_t)(w*9-4)*CH + (size_t)ln*8;
      LH_ISSUE(0); LH_ISSUE(1); LH_ISSUE(2); LH_ISSUE(3);
      LH_ISSUE(4); LH_ISSUE(5); LH_ISSUE(6); LH_ISSUE(7);
      WAITV(8);  LH_MFMA(0); LH_MFMA(1); LH_MFMA(2); LH_MFMA(3);
      LH_ISSUE(8);
      WAITV(2);  LH_MFMA(4); LH_MFMA(5); LH_MFMA(6); LH_MFMA(7);
      WAITV(0);  LH_MFMA(8);
    }
    FENCE_ACC4();
    #pragma unroll
    for (int i=0;i<4;i++){
      red[w][0][0][(ln<<2)+i]=acc00[i]; red[w][0][1][(ln<<2)+i]=acc01[i];
      red[w][1][0][(ln<<2)+i]=acc10[i]; red[w][1][1][(ln<<2)+i]=acc11[i];
    }
    __syncthreads();
    {
      float v0=0.f, v1=0.f;
      #pragma unroll
      for (int ww=0;ww<8;ww++){ v0 += red[ww][0][h_][pos]; v1 += red[ww][1][h_][pos]; }
      float hp0 = b2f(ldsout[faw0]);
      float hp1 = b2f(ldsout[faw1]);
      ldsout[faw0] = f2b(0.05f*hp0 + 0.95f*tanhf(v0 + bv0));
      ldsout[faw1] = f2b(0.05f*hp1 + 0.95f*tanhf(v1 + bv1));
    }
    __syncthreads();
    if (tid<128){
      f32x4 vv = *(const f32x4*)(ldsout + tid*8);
      st_b128_sc(H0 + (size_t)cur*S0 + (size_t)myc*CH + tid*8, vv);
    }
    drain();
    __syncthreads();
    if (tid==0) st_b16_sc(SEQ0+gidx, (unsigned)(t+1));
  }
}

// ---- proj rolling staging: 12 slots, 24 chunks ----
#define P_AP(kc_) ((kc_)<64 ? h0c+(size_t)(kc_)*CH : ((kc_)<128 ? h1c+(size_t)((kc_)-64)*CH : h2c+(size_t)((kc_)-128)*CH))
#define P_ISS(s0, c0) \
  _Pragma("unroll") \
  for (int i=0;i<6;++i){ \
    const u16* ap = P_AP(w*24+(c0)+i) + (size_t)ln*8; \
    sa[(s0)+i]=ld16_sc(ap); sb[(s0)+i]=ld16_sc(ap+512); \
  }
#define P_MM(s0, c0) \
  _Pragma("unroll") \
  for (int i=0;i<6;++i){ \
    bf16x8 a0=asbf(sa[(s0)+i]), a1=asbf(sb[(s0)+i]); \
    MFMA_AG(acc0,a0,wreg[(c0)+i]); MFMA_AG(acc1,a1,wreg[(c0)+i]); \
  }

// ---------------- projection persistent loop + final-h epilogue ----------------
static __device__ __forceinline__ void run_proj(
    const u16* __restrict__ pW, const float* __restrict__ bo,
    const u16* __restrict__ H0, const u16* __restrict__ H1, const u16* __restrict__ H2,
    float* __restrict__ out, const int* __restrict__ washp,
    u16* SEQ0, u16* SEQ1, u16* SEQ2, u16* SEQ3,
    int jt, float (*red)[2][2][256])
{
  const int tid=threadIdx.x, w=tid>>6, ln=tid&63;
  bf16x8 wreg[24];               // -> AGPRs
  #pragma unroll
  for (int ci=0;ci<24;ci++)
    wreg[ci] = *(const bf16x8*)(pW + (((size_t)jt*KCP + (w*24+ci))*64 + ln)*8);
  const int wash = *washp;
  const int h_=tid>>8, pos=tid&255, l_=pos>>2, i_=pos&3, col_=l_&15, row_=((l_>>4)<<2)+i_, b_=(h_<<4)+row_;
  const float bvp = bo[(jt<<4)+col_];

  for (int t=0;t<512;t++){
    if (tid<64){
      poll4(tid, SEQ0,(unsigned)(t+1), SEQ1,(unsigned)(t+1), SEQ2,(unsigned)(t+1),64, nullptr,0u);
    }
    __syncthreads();
    const int cur=t&7;
    const u16* h0c = H0 + (size_t)cur*S0;
    const u16* h1c = H1 + (size_t)cur*S12;
    const u16* h2c = H2 + (size_t)cur*S12;
    f32x4 sa[12], sb[12];
    f32x4 acc0={0,0,0,0}, acc1={0,0,0,0};
    asm volatile("s_nop 1" : "+v"(acc0), "+v"(acc1));
    P_ISS(0,0); P_ISS(6,6);
    WAITV(12); P_MM(0,0);  P_ISS(0,12);
    WAITV(12); P_MM(6,6);  P_ISS(6,18);
    WAITV(12); P_MM(0,12);
    WAITV(0);  P_MM(6,18);
    asm volatile("s_nop 7\n\ts_nop 7" : "+v"(acc0), "+v"(acc1));
    #pragma unroll
    for (int i=0;i<4;i++){ red[w][0][0][(ln<<2)+i]=acc0[i]; red[w][0][1][(ln<<2)+i]=acc1[i]; }
    __syncthreads();
    if (tid==0) st_b16_sc(SEQ3+jt, (unsigned)(t+1));   // reads of slot done
    if (t >= wash){
      float v=0.f;
      #pragma unroll
      for (int ww=0;ww<8;ww++) v += red[ww][0][h_][pos];
      out[(((size_t)(t-wash))*32 + b_)*128 + (jt<<4)+col_] = v + bvp;
    }
    __syncthreads();
  }
  // final hidden state: slot 7, frag layout -> [layer][b][j] fp32
  for (int q = jt*512 + tid; q < 196608; q += 4096){
    int l = q>>16, rem = q&65535, b = rem>>11, j = rem&2047;
    const u16* h = (l==0)? H0+(size_t)7*S0 : ((l==1)? H1+(size_t)7*S12 : H2+(size_t)7*S12);
    out[1966080 + q] = b2f(h[frag_addr(b,j)]);
  }
}

// ---------------- top-level persistent kernel ----------------
__global__ __launch_bounds__(512,2) void k_esn(
    const u16* __restrict__ p0, const u16* __restrict__ p1, const u16* __restrict__ p2, const u16* __restrict__ po,
    const float* __restrict__ b0, const float* __restrict__ b1, const float* __restrict__ b2, const float* __restrict__ bo,
    const float* __restrict__ input, const int* __restrict__ washp,
    u16* H0, u16* H1, u16* H2, u16* flags, float* out)
{
  __shared__ float red[8][2][2][256];
  __shared__ u16 ldsout[1024];
  const int bid = blockIdx.x;
  u16* SEQ0 = flags; u16* SEQ1 = flags+64; u16* SEQ2 = flags+128; u16* SEQ3 = flags+192;

  if (bid < 64)       run_l0 (p0, b0, input, H0, SEQ0, SEQ1, SEQ3, bid*2, red, ldsout);
  else if (bid < 128) run_l12(p1, b1, H0, S0,  H1, SEQ0, SEQ1, SEQ2, 64, SEQ3, (bid-64)*2, red, ldsout);
  else if (bid < 192) run_l12(p2, b2, H1, S12, H2, SEQ1, SEQ2, SEQ3, 8, nullptr, (bid-128)*2, red, ldsout);
  else                run_proj(po, bo, H0, H1, H2, out, washp, SEQ0, SEQ1, SEQ2, SEQ3, bid-192, red);
}

extern "C" void kernel_launch(void* const* d_in, const int* in_sizes, int n_in,
                              void* d_out, int out_size, void* d_ws, size_t ws_size,
                              hipStream_t stream)
{
  (void)in_sizes; (void)n_in; (void)out_size; (void)ws_size;
  const float* input=(const float*)d_in[0];
  const float* wih0=(const float*)d_in[1]; const float* bih0=(const float*)d_in[2];
  const float* whh0=(const float*)d_in[3];
  const float* wih1=(const float*)d_in[4]; const float* bih1=(const float*)d_in[5];
  const float* whh1=(const float*)d_in[6];
  const float* wih2=(const float*)d_in[7]; const float* bih2=(const float*)d_in[8];
  const float* whh2=(const float*)d_in[9];
  const float* wout=(const float*)d_in[10]; const float* bout=(const float*)d_in[11];
  const int* washp=(const int*)d_in[12];
  float* out=(float*)d_out;

  u16* p0=(u16*)d_ws;
  u16* p1=p0+E0P;
  u16* p2=p1+E1P;
  u16* po=p2+E1P;
  u16* H0=po+EPP;
  u16* H1=H0+(size_t)NSLOT*S0;
  u16* H2=H1+(size_t)NSLOT*S12;
  u16* flags=H2+(size_t)NSLOT*S12;   // 256 u16 seqnos (4 x 128B lines)
  size_t totbytes = ((char*)(flags+256)) - ((char*)d_ws);

  hipMemsetAsync(d_ws, 0, totbytes, stream);
  k_pack<<<dim3(2048),dim3(256),0,stream>>>(wih0,whh0,wih1,whh1,wih2,whh2,wout,p0,p1,p2,po);

  void* args[] = { (void*)&p0, (void*)&p1, (void*)&p2, (void*)&po,
                   (void*)&bih0, (void*)&bih1, (void*)&bih2, (void*)&bout,
                   (void*)&input, (void*)&washp,
                   (void*)&H0, (void*)&H1, (void*)&H2, (void*)&flags, (void*)&out };
  hipLaunchCooperativeKernel((const void*)k_esn, dim3(200), dim3(512), args, 0, stream);
}